// Round 5
// baseline (272.369 us; speedup 1.0000x reference)
//
#include <hip/hip_runtime.h>
#include <hip/hip_fp16.h>
#include <hip/hip_cooperative_groups.h>

namespace cg = cooperative_groups;

// SE3 divergence-free vector field — fused single-dispatch, v5.
//
// curl = (psi2-psi1, psi0-psi2, psi1-psi0) = (A, B, -A-B).
// Tabulate per u the two difference profiles q0=psi2-psi1, q1=psi0-psi2 with
// wcut/(8*sqrt8) folded in.  Table row: 16 half2 (64 B), one row gives both
// lerp endpoints.
//
// v4 lesson (rocprof): d_out is fine-grained memory -> atomics to it bypass
// L2/IC and serialize at the memory controller (141us, 15.9MB HBM writes).
// v5: accumulate (A,B) per node in a d_ws buffer (coarse-grained -> IC-fast
// agent atomics), then a final phase writes (a, b, -a-b) to d_out with PLAIN
// stores.  All accumulator traffic is atomic (exch-zero / add-read) so no
// XCD-L2 fence subtleties apply.
//
// ONE cooperative dispatch:
//   A: zero acc via atomicExch + blocks 0..63 build the table
//   grid.sync()
//   B: one edge per thread, 2 HW fp32 atomics into acc
//   grid.sync()
//   C: per node read acc (atomic read), write 3 floats to out
// Fallback: same phases as three plain dispatches.

#define THREADS 256
#define RTAB 2048
#define ROWH 32                          // halves per row -> 64 B stride
#define TBLOCKS ((RTAB * 8) / THREADS)   // 64 blocks of table entries

// ---------- shared device helpers ----------

__device__ __forceinline__ void stage_weights(const float* __restrict__ W1,
                                              const float* __restrict__ W2,
                                              float* sW1, float* sDW2) {
    for (int t = threadIdx.x; t < 640; t += THREADS) {
        int j = t >> 6, k = t & 63;
        sW1[j * 65 + k] = W1[t];
    }
    // difference weights: [k][2u+0] = W2c(u,2)-W2c(u,1), [k][2u+1] = W2c(u,0)-W2c(u,2)
    for (int t = threadIdx.x; t < 64 * 16; t += THREADS) {
        int k = t >> 4, j = t & 15;
        int u = j >> 1;
        const float* w2 = W2 + k * 384 + u * 32;
        sDW2[t] = (j & 1) ? (w2[0] - w2[2]) : (w2[2] - w2[1]);
    }
}

__device__ __forceinline__ void table_entry(int g, const float* sW1,
                                            const float* sDW2,
                                            __half* __restrict__ T) {
    int i = g >> 3;       // table row
    int u = g & 7;        // input feature

    float r = 3.0f * (float)i / (float)(RTAB - 1);
    float q0 = 0.f, q1 = 0.f;
    float t10 = 10.0f - (10.0f / 3.0f) * r;
    if (t10 > 0.0f) {
        // radial bump embedding: at most 2 of 10 basis functions non-zero.
        const float C0 = 8.43357306907549f;   // 1.14136*e^2 (sqrt10 cancels)
        float q  = r * (11.0f / 3.0f);
        int   jf = (int)q;
        float da = q - (float)jf;
        float db = da - 1.0f;
        float ya = fmaxf(1.0f - da * da, 1e-7f);
        float yb = fmaxf(1.0f - db * db, 1e-7f);
        int ja = jf - 1, jb = jf;
        float ea = (ja >= 0) ? C0 * __expf(-1.0f / ya) : 0.0f;
        float eb = (jb <= 9) ? C0 * __expf(-1.0f / yb) : 0.0f;
        int jac = ja < 0 ? 0 : ja;
        int jbc = jb > 9 ? 9 : jb;
        const float* w1a = sW1 + jac * 65;
        const float* w1b = sW1 + jbc * 65;
        const float* dw  = sDW2 + 2 * u;

        float a0 = 0.f, a1 = 0.f;
#pragma unroll 8
        for (int k = 0; k < 64; ++k) {
            float pre = ea * w1a[k] + eb * w1b[k];
            float h   = pre * __builtin_amdgcn_rcpf(1.0f + __expf(-pre)); // silu
            a0 = fmaf(h, dw[16 * k + 0], a0);
            a1 = fmaf(h, dw[16 * k + 1], a1);
        }
        float sc = __expf(-1.0f / t10) * 0.04419417382415922f; // wcut/(8*sqrt8)
        q0 = a0 * sc;
        q1 = a1 * sc;
    }

    __half h0 = __float2half(q0);
    __half h1 = __float2half(q1);
    size_t base = (size_t)i * ROWH + 4 * u;
    T[base + 0] = h0;                       // row i, q0 .x endpoint
    T[base + 2] = h1;                       // row i, q1 .x endpoint
    if (i > 0) {
        T[base - ROWH + 1] = h0;            // row i-1, q0 .y endpoint
        T[base - ROWH + 3] = h1;            // row i-1, q1 .y endpoint
    }
    if (i == RTAB - 1) {                    // defensive: clear unused .y slots
        T[base + 1] = h0;
        T[base + 3] = h1;
    }
}

__device__ __forceinline__ void edge_work(int e,
    const float* __restrict__ x, const float* __restrict__ pos,
    const int* __restrict__ esrc, const int* __restrict__ edst,
    const __half* __restrict__ T, float* __restrict__ acc)
{
    int s = esrc[e];
    int d = edst[e];

    float ex = pos[3 * s + 0] - pos[3 * d + 0];
    float ey = pos[3 * s + 1] - pos[3 * d + 1];
    float ez = pos[3 * s + 2] - pos[3 * d + 2];
    float r  = sqrtf(ex * ex + ey * ey + ez * ez + 1e-18f);

    if (r >= 3.0f) return;   // wcut == 0 -> edge contributes nothing

    float tq = r * ((float)(RTAB - 1) / 3.0f);
    int   i  = (int)tq;
    if (i > RTAB - 2) i = RTAB - 2;
    float f  = tq - (float)i;

    const float4* rowp = reinterpret_cast<const float4*>(T + (size_t)i * ROWH);
    const float4* xf   = reinterpret_cast<const float4*>(x + 8 * (size_t)s);
    float4 r0 = rowp[0], r1 = rowp[1], r2 = rowp[2], r3 = rowp[3];
    float4 xA = xf[0];
    float4 xB = xf[1];

    float c0 = 0.f, c1 = 0.f;
    // one float4 = entries for u2, u2+1: (q0,q1) each as half2(lo,hi)
    auto proc = [&](float4 v, float xu, float xv) {
        union { float4 f4; __half2 h[4]; } cv; cv.f4 = v;
        float2 a0 = __half22float2(cv.h[0]);
        float2 a1 = __half22float2(cv.h[1]);
        float2 a2 = __half22float2(cv.h[2]);
        float2 a3 = __half22float2(cv.h[3]);
        c0 = fmaf(xu, fmaf(f, a0.y - a0.x, a0.x), c0);
        c1 = fmaf(xu, fmaf(f, a1.y - a1.x, a1.x), c1);
        c0 = fmaf(xv, fmaf(f, a2.y - a2.x, a2.x), c0);
        c1 = fmaf(xv, fmaf(f, a3.y - a3.x, a3.x), c1);
    };
    proc(r0, xA.x, xA.y);
    proc(r1, xA.z, xA.w);
    proc(r2, xB.x, xB.y);
    proc(r3, xB.z, xB.w);

    // fire-and-forget HW fp32 atomics into COARSE-GRAINED workspace (L2/IC)
    unsafeAtomicAdd(acc + 2 * (size_t)d + 0, c0);
    unsafeAtomicAdd(acc + 2 * (size_t)d + 1, c1);
}

// ---------- fused cooperative kernel ----------

__global__ __launch_bounds__(THREADS) void se3_fused(
    const float* __restrict__ x, const float* __restrict__ pos,
    const int* __restrict__ esrc, const int* __restrict__ edst,
    const float* __restrict__ W1, const float* __restrict__ W2,
    __half* __restrict__ T, float* __restrict__ acc,
    float* __restrict__ out, int E, int nNodes)
{
    __shared__ float sW1[10 * 65];
    __shared__ float sDW2[64 * 16];

    int tid = blockIdx.x * THREADS + threadIdx.x;
    int nth = gridDim.x * THREADS;

    // phase A: zero the accumulator via atomicExch (stays at coherence point,
    // no dirty XCD-L2 lines) ...
    for (int idx = tid; idx < 2 * nNodes; idx += nth)
        atomicExch(acc + idx, 0.0f);

    // ... and build the radial table on the first 64 blocks
    if (blockIdx.x < TBLOCKS) {
        stage_weights(W1, W2, sW1, sDW2);
        __syncthreads();
        table_entry(tid, sW1, sDW2, T);   // tid < 16384 here by construction
    }

    cg::this_grid().sync();

    // phase B: edges
    for (int e = tid; e < E; e += nth)
        edge_work(e, x, pos, esrc, edst, T, acc);

    cg::this_grid().sync();

    // phase C: (a, b) -> (a, b, -a-b); atomic read = coherence-point read,
    // plain stores to d_out (fine-grained, plain stores are fine)
    for (int n = tid; n < nNodes; n += nth) {
        float a = unsafeAtomicAdd(acc + 2 * (size_t)n + 0, 0.0f);
        float b = unsafeAtomicAdd(acc + 2 * (size_t)n + 1, 0.0f);
        out[3 * (size_t)n + 0] = a;
        out[3 * (size_t)n + 1] = b;
        out[3 * (size_t)n + 2] = -a - b;
    }
}

// ---------- split fallback kernels (plain dispatches; boundaries flush L2) --

__global__ __launch_bounds__(THREADS) void se3_build_split(
    const float* __restrict__ W1, const float* __restrict__ W2,
    __half* __restrict__ T, float* __restrict__ acc, int accN)
{
    __shared__ float sW1[10 * 65];
    __shared__ float sDW2[64 * 16];

    int g = blockIdx.x * THREADS + threadIdx.x;
    for (int idx = g; idx < accN; idx += gridDim.x * THREADS)
        acc[idx] = 0.0f;

    stage_weights(W1, W2, sW1, sDW2);
    __syncthreads();
    if (g < RTAB * 8) table_entry(g, sW1, sDW2, T);
}

__global__ __launch_bounds__(THREADS) void se3_edge_split(
    const float* __restrict__ x, const float* __restrict__ pos,
    const int* __restrict__ esrc, const int* __restrict__ edst,
    const __half* __restrict__ T, float* __restrict__ acc, int E)
{
    int e = blockIdx.x * THREADS + threadIdx.x;
    if (e < E) edge_work(e, x, pos, esrc, edst, T, acc);
}

__global__ __launch_bounds__(THREADS) void se3_reduce_split(
    const float* __restrict__ acc, float* __restrict__ out, int nNodes)
{
    int n = blockIdx.x * THREADS + threadIdx.x;
    if (n >= nNodes) return;
    float a = acc[2 * (size_t)n + 0];
    float b = acc[2 * (size_t)n + 1];
    out[3 * (size_t)n + 0] = a;
    out[3 * (size_t)n + 1] = b;
    out[3 * (size_t)n + 2] = -a - b;
}

// ---------- host ----------

extern "C" void kernel_launch(void* const* d_in, const int* in_sizes, int n_in,
                              void* d_out, int out_size, void* d_ws, size_t ws_size,
                              hipStream_t stream) {
    const float* x    = (const float*)d_in[0];
    const float* pos  = (const float*)d_in[1];
    const int*   esrc = (const int*)d_in[2];
    const int*   edst = (const int*)d_in[3];
    const float* W1   = (const float*)d_in[4];
    const float* W2   = (const float*)d_in[5];
    float* out = (float*)d_out;

    int E      = in_sizes[2];
    int outN   = out_size;        // B*N*3 floats
    int nNodes = outN / 3;

    size_t tableBytes = (size_t)RTAB * ROWH * sizeof(__half);  // 128 KB
    __half* T   = (__half*)d_ws;
    float*  acc = (float*)((char*)d_ws + tableBytes);          // 2*nNodes floats

    // co-residency-safe grid for the cooperative launch
    int blocksPerCU = 0;
    if (hipOccupancyMaxActiveBlocksPerMultiprocessor(
            &blocksPerCU, se3_fused, THREADS, 0) != hipSuccess || blocksPerCU < 1)
        blocksPerCU = 2;   // conservative
    int nCU = 0;
    int dev = 0;
    (void)hipGetDevice(&dev);
    if (hipDeviceGetAttribute(&nCU, hipDeviceAttributeMultiprocessorCount, dev)
            != hipSuccess || nCU < 1)
        nCU = 256;

    long cap  = (long)blocksPerCU * (long)nCU;
    int  grid = (E + THREADS - 1) / THREADS;     // 1 edge per thread if it fits
    if ((long)grid > cap) grid = (int)cap;
    if (grid < TBLOCKS) grid = TBLOCKS;          // table needs >= 64 blocks

    void* args[] = {(void*)&x, (void*)&pos, (void*)&esrc, (void*)&edst,
                    (void*)&W1, (void*)&W2, (void*)&T, (void*)&acc,
                    (void*)&out, (void*)&E, (void*)&nNodes};

    hipError_t err = hipLaunchCooperativeKernel(
        se3_fused, dim3(grid), dim3(THREADS), args, 0, stream);

    if (err != hipSuccess) {
        (void)hipGetLastError();   // clear sticky error, use plain dispatches
        se3_build_split<<<TBLOCKS, THREADS, 0, stream>>>(
            W1, W2, T, acc, 2 * nNodes);
        se3_edge_split<<<(E + THREADS - 1) / THREADS, THREADS, 0, stream>>>(
            x, pos, esrc, edst, T, acc, E);
        se3_reduce_split<<<(nNodes + THREADS - 1) / THREADS, THREADS, 0, stream>>>(
            acc, out, nNodes);
    }
}

// Round 6
// 96.479 us; speedup vs baseline: 2.8231x; 2.8231x over previous
//
#include <hip/hip_runtime.h>
#include <hip/hip_fp16.h>

// SE3 divergence-free vector field — difference-profile table, v6.
// Structure = v3.1 (measured best, 95.8us): 3 plain dispatches, privatized
// fire-and-forget fp32 atomics into coarse d_ws, kernel boundaries provide
// all coherence.  v4/v5 lesson: device-scope atomics are MEMORY-SIDE (IC),
// ~15-20B HBM writethrough each; returning atomics and atomicExch are worse;
// cooperative fusion loses.  v6 deltas vs v3.1:
//   - ncopies 8 -> 16 (halve per-line atomic contention)
//   - pos repacked to aligned float4 in build kernel (2 dwordx4 gathers/edge
//     instead of 6 scattered dwords)
//   - difference-profile weights folded at stage time (from v4)

#define THREADS 256
#define RTAB 2048
#define ROWH 32                          // halves per row -> 64 B stride
#define TBLOCKS ((RTAB * 8) / THREADS)   // 64 blocks of table entries
#define BBLOCKS 256                      // build-kernel grid
#define MAXCOPIES 16

__global__ __launch_bounds__(THREADS) void se3_build_table(
    const float* __restrict__ W1,   // (10, 64)
    const float* __restrict__ W2,   // (64, 384)
    const float* __restrict__ pos,  // (nNodes, 3)
    __half* __restrict__ T,         // (RTAB, ROWH) halves
    float4* __restrict__ pos4,      // (nNodes) padded positions
    float4* __restrict__ zbuf,      // copies region to zero
    int nNodes, int zcount4)
{
    __shared__ float sW1[10 * 65];
    __shared__ float sDW2[64 * 16];

    int g   = blockIdx.x * THREADS + threadIdx.x;
    int nth = gridDim.x * THREADS;

    // zero the privatized accumulators (plain stores; kernel boundary flushes)
    float4 z = make_float4(0.f, 0.f, 0.f, 0.f);
    for (int idx = g; idx < zcount4; idx += nth)
        zbuf[idx] = z;

    // repack pos (12B rows) into aligned float4 rows
    for (int n = g; n < nNodes; n += nth) {
        const float* p = pos + 3 * (size_t)n;
        pos4[n] = make_float4(p[0], p[1], p[2], 0.f);
    }

    if (blockIdx.x >= TBLOCKS) return;

    for (int t = threadIdx.x; t < 640; t += THREADS) {
        int j = t >> 6, k = t & 63;
        sW1[j * 65 + k] = W1[t];
    }
    // difference weights: [k][2u+0]=W2c(u,2)-W2c(u,1), [k][2u+1]=W2c(u,0)-W2c(u,2)
    for (int t = threadIdx.x; t < 64 * 16; t += THREADS) {
        int k = t >> 4, j = t & 15;
        int u = j >> 1;
        const float* w2 = W2 + k * 384 + u * 32;
        sDW2[t] = (j & 1) ? (w2[0] - w2[2]) : (w2[2] - w2[1]);
    }
    __syncthreads();

    int i = g >> 3;       // table row
    int u = g & 7;        // input feature

    float r = 3.0f * (float)i / (float)(RTAB - 1);
    float q0 = 0.f, q1 = 0.f;
    float t10 = 10.0f - (10.0f / 3.0f) * r;
    if (t10 > 0.0f) {
        // radial bump embedding: at most 2 of 10 basis functions non-zero.
        const float C0 = 8.43357306907549f;   // 1.14136*e^2 (sqrt10 cancels)
        float q  = r * (11.0f / 3.0f);
        int   jf = (int)q;
        float da = q - (float)jf;
        float db = da - 1.0f;
        float ya = fmaxf(1.0f - da * da, 1e-7f);
        float yb = fmaxf(1.0f - db * db, 1e-7f);
        int ja = jf - 1, jb = jf;
        float ea = (ja >= 0) ? C0 * __expf(-1.0f / ya) : 0.0f;
        float eb = (jb <= 9) ? C0 * __expf(-1.0f / yb) : 0.0f;
        int jac = ja < 0 ? 0 : ja;
        int jbc = jb > 9 ? 9 : jb;
        const float* w1a = sW1 + jac * 65;
        const float* w1b = sW1 + jbc * 65;
        const float* dw  = sDW2 + 2 * u;

        float a0 = 0.f, a1 = 0.f;
#pragma unroll 8
        for (int k = 0; k < 64; ++k) {
            float pre = ea * w1a[k] + eb * w1b[k];
            float h   = pre * __builtin_amdgcn_rcpf(1.0f + __expf(-pre)); // silu
            a0 = fmaf(h, dw[16 * k + 0], a0);
            a1 = fmaf(h, dw[16 * k + 1], a1);
        }
        float sc = __expf(-1.0f / t10) * 0.04419417382415922f; // wcut/(8*sqrt8)
        q0 = a0 * sc;
        q1 = a1 * sc;
    }

    __half h0 = __float2half(q0);
    __half h1 = __float2half(q1);
    size_t base = (size_t)i * ROWH + 4 * u;
    T[base + 0] = h0;                       // row i, q0 .x endpoint
    T[base + 2] = h1;                       // row i, q1 .x endpoint
    if (i > 0) {
        T[base - ROWH + 1] = h0;            // row i-1, q0 .y endpoint
        T[base - ROWH + 3] = h1;            // row i-1, q1 .y endpoint
    }
    if (i == RTAB - 1) {                    // defensive: clear unused .y slots
        T[base + 1] = h0;
        T[base + 3] = h1;
    }
}

__global__ __launch_bounds__(THREADS) void se3_edge_kernel(
    const float*  __restrict__ x,     // (nNodes, 8)
    const float4* __restrict__ pos4,  // (nNodes)
    const int*    __restrict__ esrc,  // (E,)
    const int*    __restrict__ edst,  // (E,)
    const __half* __restrict__ T,     // (RTAB, ROWH)
    float*        __restrict__ outbuf,// ncopies x outN2, pre-zeroed
    int E, int ncopies, int outN2)
{
    int e = blockIdx.x * THREADS + threadIdx.x;
    if (e >= E) return;

    int s = esrc[e];
    int d = edst[e];

    float4 ps = pos4[s];
    float4 pd = pos4[d];
    float ex = ps.x - pd.x;
    float ey = ps.y - pd.y;
    float ez = ps.z - pd.z;
    float r  = sqrtf(ex * ex + ey * ey + ez * ez + 1e-18f);

    if (r >= 3.0f) return;   // wcut == 0 -> edge contributes nothing

    float tq = r * ((float)(RTAB - 1) / 3.0f);
    int   i  = (int)tq;
    if (i > RTAB - 2) i = RTAB - 2;
    float f  = tq - (float)i;

    const float4* rowp = reinterpret_cast<const float4*>(T + (size_t)i * ROWH);
    const float4* xf   = reinterpret_cast<const float4*>(x + 8 * (size_t)s);
    float4 r0 = rowp[0], r1 = rowp[1], r2 = rowp[2], r3 = rowp[3];
    float4 xA = xf[0];
    float4 xB = xf[1];

    float c0 = 0.f, c1 = 0.f;
    // one float4 = entries for u2, u2+1: (q0,q1) each as half2(lo,hi)
    auto proc = [&](float4 v, float xu, float xv) {
        union { float4 f4; __half2 h[4]; } cv; cv.f4 = v;
        float2 a0 = __half22float2(cv.h[0]);
        float2 a1 = __half22float2(cv.h[1]);
        float2 a2 = __half22float2(cv.h[2]);
        float2 a3 = __half22float2(cv.h[3]);
        c0 = fmaf(xu, fmaf(f, a0.y - a0.x, a0.x), c0);
        c1 = fmaf(xu, fmaf(f, a1.y - a1.x, a1.x), c1);
        c0 = fmaf(xv, fmaf(f, a2.y - a2.x, a2.x), c0);
        c1 = fmaf(xv, fmaf(f, a3.y - a3.x, a3.x), c1);
    };
    proc(r0, xA.x, xA.y);
    proc(r1, xA.z, xA.w);
    proc(r2, xB.x, xB.y);
    proc(r3, xB.z, xB.w);

    // fire-and-forget HW fp32 atomics, privatized over ncopies copies
    float* ob = outbuf + (size_t)(blockIdx.x % ncopies) * outN2 + 2 * d;
    unsafeAtomicAdd(ob + 0, c0);
    unsafeAtomicAdd(ob + 1, c1);
}

__global__ __launch_bounds__(THREADS) void se3_reduce_kernel(
    const float* __restrict__ ws, float* __restrict__ out,
    int nNodes, int ncopies, int outN2)
{
    int n = blockIdx.x * THREADS + threadIdx.x;
    if (n >= nNodes) return;
    const float2* w = reinterpret_cast<const float2*>(ws);
    int stride2 = outN2 >> 1;
    float a = 0.f, b = 0.f;
    for (int c = 0; c < ncopies; ++c) {
        float2 v = w[(size_t)c * stride2 + n];
        a += v.x; b += v.y;
    }
    out[3 * (size_t)n + 0] = a;
    out[3 * (size_t)n + 1] = b;
    out[3 * (size_t)n + 2] = -a - b;
}

extern "C" void kernel_launch(void* const* d_in, const int* in_sizes, int n_in,
                              void* d_out, int out_size, void* d_ws, size_t ws_size,
                              hipStream_t stream) {
    const float* x    = (const float*)d_in[0];
    const float* pos  = (const float*)d_in[1];
    const int*   esrc = (const int*)d_in[2];
    const int*   edst = (const int*)d_in[3];
    const float* W1   = (const float*)d_in[4];
    const float* W2   = (const float*)d_in[5];
    float* out = (float*)d_out;

    int E      = in_sizes[2];
    int outN   = out_size;        // B*N*3 floats
    int nNodes = outN / 3;
    int outN2  = 2 * nNodes;      // floats per accumulator copy

    size_t tableBytes = (size_t)RTAB * ROWH * sizeof(__half);  // 128 KB
    size_t pos4Bytes  = (size_t)nNodes * sizeof(float4);       // 512 KB
    __half* T      = (__half*)d_ws;
    float4* pos4   = (float4*)((char*)d_ws + tableBytes);
    float*  copies = (float*)((char*)d_ws + tableBytes + pos4Bytes);

    size_t copyBytes = (size_t)outN2 * sizeof(float);
    int ncopies = 1;
    if (ws_size > tableBytes + pos4Bytes + copyBytes) {
        size_t rem = ws_size - tableBytes - pos4Bytes;
        int nc = (int)(rem / copyBytes);
        if (nc > MAXCOPIES) nc = MAXCOPIES;
        if (nc < 1) nc = 1;
        ncopies = nc;
    }
    int zcount4 = (int)(((size_t)ncopies * outN2) / 4);

    se3_build_table<<<BBLOCKS, THREADS, 0, stream>>>(
        W1, W2, pos, T, pos4, (float4*)copies, nNodes, zcount4);

    se3_edge_kernel<<<(E + THREADS - 1) / THREADS, THREADS, 0, stream>>>(
        x, pos4, esrc, edst, T, copies, E, ncopies, outN2);

    se3_reduce_kernel<<<(nNodes + THREADS - 1) / THREADS, THREADS, 0, stream>>>(
        copies, out, nNodes, ncopies, outN2);
}